// Round 2
// baseline (560.000 us; speedup 1.0000x reference)
//
#include <hip/hip_runtime.h>

// VoxelShuffle, R=2, V=8, sequential pairing. FP32 in/out.
// Output 0: feats = features.reshape(N*8, C/8) -> flat identity copy (float32).
// Output 1: new_indices[n*8+v] = (b, 2z+oz, 2y+oy, 2x+ox) as float32 values.
// Offset order (argsort of i*4+k*2+j over meshgrid(i,j,k) ij-order):
//   v: 0..7 -> oz=(v>>2)&1, ox=(v>>1)&1, oy=v&1.
// R1 post-mortem: d_out is float32 (error 259.56 = bf16-pair alias of index
// value 255 inside the fp32 feats region), not bf16.

__global__ __launch_bounds__(256) void VoxelShuffle_kernel(
    const uint4* __restrict__ feat4,    // features as 16B chunks (4 fp32)
    const int4*  __restrict__ idx,      // [N] of (b,z,y,x)
    uint4*       __restrict__ outf4,    // feats output, 16B chunks
    float4*      __restrict__ outi,     // fp32 index rows, 16B each
    int n_copy,                         // NC/4 16B-chunks to copy
    int n_rows)                         // N*8 output index rows
{
    int tid = blockIdx.x * blockDim.x + threadIdx.x;
    if (tid < n_copy) {
        // ---- feature copy: 16 B per lane, fully coalesced ----
        outf4[tid] = feat4[tid];
    } else {
        int m = tid - n_copy;
        if (m < n_rows) {
            // ---- one index row per lane: 16 B float4 store, coalesced ----
            int n = m >> 3;
            int v = m & 7;
            int4 q = idx[n];            // (b, z, y, x); 8 lanes share -> L1 hit
            float4 o;
            o.x = (float)q.x;                          // b
            o.y = (float)((q.y << 1) | ((v >> 2) & 1)); // 2z+oz
            o.z = (float)((q.z << 1) | (v & 1));        // 2y+oy
            o.w = (float)((q.w << 1) | ((v >> 1) & 1)); // 2x+ox
            outi[m] = o;
        }
    }
}

extern "C" void kernel_launch(void* const* d_in, const int* in_sizes, int n_in,
                              void* d_out, int out_size, void* d_ws, size_t ws_size,
                              hipStream_t stream) {
    const uint4* feat = (const uint4*)d_in[0];   // fp32 features, 16B chunks
    const int4*  idx  = (const int4*)d_in[1];    // int32 [N,4]

    const int NC = in_sizes[0];        // N*C = 67,108,864 floats
    const int N  = in_sizes[1] >> 2;   // 1,048,576

    const int n_copy = NC >> 2;        // 16,777,216 16B chunks
    const int n_rows = N << 3;         // 8,388,608 index rows

    uint4*  outf = (uint4*)d_out;
    float4* outi = (float4*)((float*)d_out + (size_t)NC);

    long long total = (long long)n_copy + (long long)n_rows;
    int blocks = (int)((total + 255) / 256);

    VoxelShuffle_kernel<<<blocks, 256, 0, stream>>>(feat, idx, outf, outi,
                                                    n_copy, n_rows);
}